// Round 17
// baseline (5016.101 us; speedup 1.0000x reference)
//
#include <hip/hip_runtime.h>

#define TT 512
#define BB 64
#define II 1024
#define HH 1024
#define GG 4096   /* 4*H */
#define BH 65536  /* B*H */
#define NBLK 128

typedef __attribute__((ext_vector_type(8))) short bf16x8;
typedef __attribute__((ext_vector_type(4))) float f32x4;
typedef __attribute__((ext_vector_type(4))) unsigned u32x4;

__device__ __forceinline__ float bf2f(unsigned short u) {
  union { unsigned int i; float f; } v; v.i = ((unsigned int)u) << 16; return v.f;
}
__device__ __forceinline__ unsigned short f2bf(float f) {
  union { float f; unsigned int i; } v; v.f = f;
  return (unsigned short)((v.i + 0x7FFFu + ((v.i >> 16) & 1u)) >> 16);
}
__device__ __forceinline__ bf16x8 pack8(float4 a, float4 b) {
  union { bf16x8 v; unsigned short u[8]; } p;
  p.u[0] = f2bf(a.x); p.u[1] = f2bf(a.y); p.u[2] = f2bf(a.z); p.u[3] = f2bf(a.w);
  p.u[4] = f2bf(b.x); p.u[5] = f2bf(b.y); p.u[6] = f2bf(b.z); p.u[7] = f2bf(b.w);
  return p.v;
}
__device__ __forceinline__ float sigmoid_f(float x) { return 1.0f / (1.0f + __expf(-x)); }
__device__ __forceinline__ float tanh_f(float x) {
  float e = __expf(-2.0f * fabsf(x));
  float t = (1.0f - e) / (1.0f + e);
  return copysignf(t, x);
}

__device__ __forceinline__ void st32_uc(unsigned* p, unsigned v) {
  __hip_atomic_store(p, v, __ATOMIC_RELAXED, __HIP_MEMORY_SCOPE_AGENT);
}
__device__ __forceinline__ unsigned ld32_uc(const unsigned* p) {
  return __hip_atomic_load(p, __ATOMIC_RELAXED, __HIP_MEMORY_SCOPE_AGENT);
}
__device__ __forceinline__ void st128_uc(void* p, u32x4 v) {
  asm volatile("global_store_dwordx4 %0, %1, off sc0 sc1" :: "v"(p), "v"(v) : "memory");
}
// LDS monotonic counters (add/store from ONE lane per wave)
__device__ __forceinline__ void lds_add_rel(int* p) {
  __hip_atomic_fetch_add(p, 1, __ATOMIC_RELEASE, __HIP_MEMORY_SCOPE_WORKGROUP);
}
__device__ __forceinline__ int lds_ld_acq(const int* p) {
  return __hip_atomic_load(p, __ATOMIC_ACQUIRE, __HIP_MEMORY_SCOPE_WORKGROUP);
}
__device__ __forceinline__ void lds_st_rel(int* p, int v) {
  __hip_atomic_store(p, v, __ATOMIC_RELEASE, __HIP_MEMORY_SCOPE_WORKGROUP);
}

// ---------------- x f32 -> bf16 chunk conversion ----------------
__global__ __launch_bounds__(256) void wdlstm_xconv(
    const float* __restrict__ xc, unsigned short* __restrict__ xbf, int n4) {
  int stride = gridDim.x * blockDim.x;
  for (int i = blockIdx.x * blockDim.x + threadIdx.x; i < n4; i += stride) {
    float4 v = *(const float4*)(xc + (size_t)i * 4);
    unsigned short o[4] = {f2bf(v.x), f2bf(v.y), f2bf(v.z), f2bf(v.w)};
    *(unsigned long long*)(xbf + (size_t)i * 4) = *(unsigned long long*)o;
  }
}

// ------- fused recurrence over [t0, t0+tc): split-K, register-resident weights -------
// 128 WGs x 512 threads. Waves 0-3: recurrence, wave kq owns K-quarter [256kq,256kq+256);
// Wh-quarter lives in 64 VGPRs (loaded+masked once). Partials -> Dpart[4][64][33] f32.
// Waves 4-7: gx engine, same split-K; Wi-quarter in 64 VGPRs; bf16 partials into
// depth-2 Dgx ring. EW sums 4+4 partials + bias. ZERO per-step LDS B-reads.
// Sync: wave 0 polls 128 per-block flags, posts LDS epoch (flat R15 scheme).
__global__ __launch_bounds__(512) void wdlstm_fused(
    const float* __restrict__ w_hh, const float* __restrict__ hh_mask,
    const float* __restrict__ w_ih,
    const float* __restrict__ b_ih, const float* __restrict__ b_hh,
    const unsigned short* __restrict__ xbf,  // [tc][B][I] bf16
    float* __restrict__ out, float* __restrict__ c_state,
    unsigned* __restrict__ flags,            // [NBLK] 64B-padded, monotonic t+1
    unsigned short* __restrict__ hinit,      // [BH] cross-chunk h carry
    unsigned short* __restrict__ hring,      // [tc][BH] fresh slot per step
    int t0, int tc) {
  __shared__ float Dpart[4][64][33];                 // split-K rec partials (f32)
  __shared__ unsigned short Dgx[2][4][32][72];       // gx partials ring (bf16)
  __shared__ __align__(16) unsigned Hs[64][4];       // h pack: [b][wv] = cols 2wv,2wv+1
  __shared__ float bias_lds[32];
  __shared__ int syncv[8];   // 0:cnt_D 1:cnt_EW 2..5:gx_done[w2] 7:epoch

  const int tid = threadIdx.x;
  const int wv  = tid >> 6, l = tid & 63;
  const int ln  = l & 15, lq = l >> 4;
  const int j0h = blockIdx.x * 8;

  if (tid < 8) syncv[tid] = 0;
  if (tid < 32) {
    int gcol = (tid >> 3) * HH + j0h + (tid & 7);
    bias_lds[tid] = b_ih[gcol] + b_hh[gcol];
  }
  __syncthreads();   // the ONLY whole-block barrier

  if (wv < 4) {
    // ============ recurrence role: wave kq owns K-quarter ============
    __builtin_amdgcn_s_setprio(1);
    const int kq = wv;
    const int b_ew = l;                  // elementwise: batch row
    const int jj0  = 2 * wv;             // elementwise: col pair

    // Wh-quarter -> registers (masked), once
    bf16x8 Bh[2][8];
#pragma unroll
    for (int ni = 0; ni < 2; ++ni)
#pragma unroll
      for (int kc = 0; kc < 8; ++kc) {
        int n = 16 * ni + ln;
        int wrow = (n >> 3) * HH + j0h + (n & 7);
        int k0 = kq * 256 + kc * 32 + lq * 8;
        const float* sw = w_hh   + (size_t)wrow * HH + k0;
        const float* sm = hh_mask + (size_t)wrow * HH + k0;
        float4 w0 = *(const float4*)sw, w1 = *(const float4*)(sw + 4);
        float4 m0 = *(const float4*)sm, m1 = *(const float4*)(sm + 4);
        float4 p0 = {w0.x * m0.x, w0.y * m0.y, w0.z * m0.z, w0.w * m0.w};
        float4 p1 = {w1.x * m1.x, w1.y * m1.y, w1.z * m1.z, w1.w * m1.w};
        Bh[ni][kc] = pack8(p0, p1);
      }

    float c_reg[2];
    if (t0 == 0) { c_reg[0] = c_reg[1] = 0.f; }
    else {
      float2 cv = *(const float2*)(c_state + (size_t)b_ew * HH + j0h + jj0);
      c_reg[0] = cv.x; c_reg[1] = cv.y;
    }
    float* hn_out = out + (size_t)TT * BH;
    float* cn_out = hn_out + BH;

    for (int lt = 0; lt < tc; ++lt) {
      const int t = t0 + lt;
      f32x4 acc[4][2];
#pragma unroll
      for (int mi = 0; mi < 4; ++mi)
#pragma unroll
        for (int ni = 0; ni < 2; ++ni) acc[mi][ni] = (f32x4){0.f, 0.f, 0.f, 0.f};

      if (t > 0) {
        if (lt > 0) {      // hinit path is dispatch-boundary-synced
          if (wv == 0) {
            const unsigned* f0 = flags + (2 * l) * 16;
            const unsigned* f1 = flags + (2 * l + 1) * 16;
            while ((int)ld32_uc(f0) < t || (int)ld32_uc(f1) < t)
              __builtin_amdgcn_s_sleep(1);
            if (l == 0) lds_st_rel(&syncv[7], t);      // epoch
          } else {
            while (lds_ld_acq(&syncv[7]) < t) {}
          }
        }
        const char* hpb = (lt == 0) ? (const char*)hinit
                                    : (const char*)(hring + (size_t)(lt - 1) * BH);
        const char* base = hpb + ((size_t)ln * 1024 + kq * 256 + lq * 8) * 2;
#pragma unroll
        for (int h = 0; h < 2; ++h) {   // mi-halves: {0,1} then {2,3}
          bf16x8 A[2][8];
#pragma unroll
          for (int m2 = 0; m2 < 2; ++m2)
#pragma unroll
            for (int kc = 0; kc < 8; ++kc)
              A[m2][kc] = *(const bf16x8*)(base + (size_t)(h * 2 + m2) * 32768 + kc * 64);
#pragma unroll
          for (int kc = 0; kc < 8; ++kc)
#pragma unroll
            for (int m2 = 0; m2 < 2; ++m2)
#pragma unroll
              for (int ni = 0; ni < 2; ++ni)
                acc[h * 2 + m2][ni] = __builtin_amdgcn_mfma_f32_16x16x32_bf16(
                    A[m2][kc], Bh[ni][kc], acc[h * 2 + m2][ni], 0, 0, 0);
        }
      }
      // write split-K partial (WAR safe: epoch(t) implies EW(lt-1) done everywhere)
#pragma unroll
      for (int mi = 0; mi < 4; ++mi)
#pragma unroll
        for (int ni = 0; ni < 2; ++ni)
#pragma unroll
          for (int r = 0; r < 4; ++r)
            Dpart[kq][16 * mi + 4 * lq + r][16 * ni + ln] = acc[mi][ni][r];
      if (l == 0) lds_add_rel(&syncv[0]);                 // cnt_D
      {
        const int tgt = 4 * (lt + 1);
        while (lds_ld_acq(&syncv[0]) < tgt) {}
        while (lds_ld_acq(&syncv[2]) < lt + 1 || lds_ld_acq(&syncv[3]) < lt + 1 ||
               lds_ld_acq(&syncv[4]) < lt + 1 || lds_ld_acq(&syncv[5]) < lt + 1)
          __builtin_amdgcn_s_sleep(1);
      }

      // EW: lane -> (b = l, cols jj0, jj0+1); gate col n = g*8 + jj
      const int slot = lt & 1;
      float hq[2];
#pragma unroll
      for (int q = 0; q < 2; ++q) {
        int jj = jj0 + q;
        float gs[4];
#pragma unroll
        for (int g = 0; g < 4; ++g) {
          int n = g * 8 + jj;
          float s = bias_lds[n];
#pragma unroll
          for (int k2 = 0; k2 < 4; ++k2) s += Dpart[k2][b_ew][n];
#pragma unroll
          for (int k2 = 0; k2 < 4; ++k2) s += bf2f(Dgx[slot][k2][n][b_ew]);
          gs[g] = s;
        }
        float ig = sigmoid_f(gs[0]);
        float fg = sigmoid_f(gs[1]);
        float gg = tanh_f(gs[2]);
        float og = sigmoid_f(gs[3]);
        c_reg[q] = fg * c_reg[q] + ig * gg;
        hq[q] = og * tanh_f(c_reg[q]);
      }
      *(float2*)(out + (size_t)t * BH + (size_t)b_ew * HH + j0h + jj0) = make_float2(hq[0], hq[1]);
      Hs[b_ew][wv] = (unsigned)f2bf(hq[0]) | ((unsigned)f2bf(hq[1]) << 16);
      if (t == TT - 1) {
        *(float2*)(hn_out + (size_t)b_ew * HH + j0h + jj0) = make_float2(hq[0], hq[1]);
        *(float2*)(cn_out + (size_t)b_ew * HH + j0h + jj0) = make_float2(c_reg[0], c_reg[1]);
      }
      if (l == 0) lds_add_rel(&syncv[1]);                 // cnt_EW

      if (wv == 0) {
        const int tgt = 4 * (lt + 1);
        while (lds_ld_acq(&syncv[1]) < tgt) {}
        // publish: 64 lanes, one 16B row-slice each
        u32x4 hv4 = *(const u32x4*)&Hs[l][0];
        char* dst = (char*)hring + ((size_t)lt * BH + (size_t)l * HH + j0h) * 2;
        st128_uc(dst, hv4);
        if (lt == tc - 1)   // cross-chunk carry (dispatch-end flush covers it)
          *(u32x4*)((char*)hinit + ((size_t)l * HH + j0h) * 2) = hv4;
        asm volatile("s_waitcnt vmcnt(0)" ::: "memory");
        if (l == 0) st32_uc(&flags[blockIdx.x * 16], (unsigned)(t + 1));
      }
    }
    *(float2*)(c_state + (size_t)b_ew * HH + j0h + jj0) = make_float2(c_reg[0], c_reg[1]);

  } else {
    // ============ gx engine role: wave w2 owns K-quarter of x@Wih^T ============
    const int w2 = wv - 4;
    // Wi-quarter -> registers, once
    bf16x8 Bi[2][8];
#pragma unroll
    for (int ni = 0; ni < 2; ++ni)
#pragma unroll
      for (int kc = 0; kc < 8; ++kc) {
        int n = 16 * ni + ln;
        int wrow = (n >> 3) * HH + j0h + (n & 7);
        int k0 = w2 * 256 + kc * 32 + lq * 8;
        const float* si = w_ih + (size_t)wrow * II + k0;
        float4 a0 = *(const float4*)si, a1 = *(const float4*)(si + 4);
        Bi[ni][kc] = pack8(a0, a1);
      }

    for (int s = 0; s < tc; ++s) {
      if (s >= 2) {   // ring WAR: EW of step s-2 must be done
        const int tgt = 4 * (s - 1);
        while (lds_ld_acq(&syncv[1]) < tgt) __builtin_amdgcn_s_sleep(1);
      }
      f32x4 acc[4][2];
#pragma unroll
      for (int mi = 0; mi < 4; ++mi)
#pragma unroll
        for (int ni = 0; ni < 2; ++ni) acc[mi][ni] = (f32x4){0.f, 0.f, 0.f, 0.f};
      const char* base = (const char*)xbf + (size_t)s * BH * 2
                         + ((size_t)ln * 1024 + w2 * 256 + lq * 8) * 2;
#pragma unroll
      for (int h = 0; h < 2; ++h) {
        bf16x8 A[2][8];
#pragma unroll
        for (int m2 = 0; m2 < 2; ++m2)
#pragma unroll
          for (int kc = 0; kc < 8; ++kc)
            A[m2][kc] = *(const bf16x8*)(base + (size_t)(h * 2 + m2) * 32768 + kc * 64);
#pragma unroll
        for (int kc = 0; kc < 8; ++kc)
#pragma unroll
          for (int m2 = 0; m2 < 2; ++m2)
#pragma unroll
            for (int ni = 0; ni < 2; ++ni)
              acc[h * 2 + m2][ni] = __builtin_amdgcn_mfma_f32_16x16x32_bf16(
                  A[m2][kc], Bi[ni][kc], acc[h * 2 + m2][ni], 0, 0, 0);
      }
      const int slot = s & 1;
#pragma unroll
      for (int mi = 0; mi < 4; ++mi)
#pragma unroll
        for (int ni = 0; ni < 2; ++ni) {
          unsigned short p[4] = {f2bf(acc[mi][ni][0]), f2bf(acc[mi][ni][1]),
                                 f2bf(acc[mi][ni][2]), f2bf(acc[mi][ni][3])};
          *(unsigned long long*)&Dgx[slot][w2][16 * ni + ln][16 * mi + 4 * lq] =
              *(unsigned long long*)p;
        }
      if (l == 0) lds_st_rel(&syncv[2 + w2], s + 1);   // gx_done[w2]
    }
  }
}

extern "C" void kernel_launch(void* const* d_in, const int* in_sizes, int n_in,
                              void* d_out, int out_size, void* d_ws, size_t ws_size,
                              hipStream_t stream) {
  const float* x       = (const float*)d_in[0];
  const float* w_ih    = (const float*)d_in[1];
  const float* w_hh    = (const float*)d_in[2];
  const float* b_ih    = (const float*)d_in[3];
  const float* b_hh    = (const float*)d_in[4];
  const float* hh_mask = (const float*)d_in[5];
  float* out           = (float*)d_out;

  char* ws = (char*)d_ws;
  float* c_state        = (float*)ws;                           // 262144 B
  unsigned* flags       = (unsigned*)(ws + 262144);             // 8192 B (128 x 64B)
  unsigned short* hinit = (unsigned short*)(ws + 270336);       // 131072 B
  unsigned short* hring = (unsigned short*)(ws + 401408);       // TC x 131072 B
  // xbf placed after hring (TC-dependent)

  const long long fixed = 401408;
  const long long per_t = 131072 + 131072;
  long long avail = (long long)ws_size - fixed;
  int TC = (int)(avail / per_t);
  if (TC > TT) TC = TT;
  if (TC < 2) TC = 2;
  unsigned short* xbf = (unsigned short*)(ws + 401408 + (size_t)TC * 131072);

  // flags monotonic across chunks; reset once per launch (replay-safe)
  hipMemsetAsync(flags, 0, 8192, stream);

  for (int t0 = 0; t0 < TT; t0 += TC) {
    int tc = TT - t0 < TC ? TT - t0 : TC;
    const float* xc = x + (size_t)t0 * BB * II;
    wdlstm_xconv<<<1024, 256, 0, stream>>>(xc, xbf, tc * BH / 4);
    wdlstm_fused<<<NBLK, 512, 0, stream>>>(w_hh, hh_mask, w_ih, b_ih, b_hh, xbf,
                                           out, c_state, flags, hinit, hring, t0, tc);
  }
}